// Round 1
// baseline (31743.597 us; speedup 1.0000x reference)
//
#include <hip/hip_runtime.h>
#include <math.h>

#define N_NODES 100000
#define N_EDGES 400000
#define IN_DIM 100
#define D 200
#define NUM_STEPS 4

// ---------------- pad: h[:, :100] = x, h[:, 100:] = 0 ----------------
__global__ void pad_kernel(const float* __restrict__ x, float* __restrict__ h) {
    int idx = blockIdx.x * blockDim.x + threadIdx.x;
    if (idx >= N_NODES * D) return;
    int n = idx / D, d = idx % D;
    h[idx] = (d < IN_DIM) ? x[n * IN_DIM + d] : 0.0f;
}

// ---------------- m = h @ W  (W is [200,200] row-major) ----------------
#define TN 64
__global__ __launch_bounds__(256) void gemm_hW(const float* __restrict__ h,
                                               const float* __restrict__ W,
                                               float* __restrict__ m) {
    __shared__ float hs[TN][D + 1];
    int node0 = blockIdx.x * TN;
    for (int i = threadIdx.x; i < TN * D; i += 256) {
        int r = i / D, c = i % D;
        int n = node0 + r;
        hs[r][c] = (n < N_NODES) ? h[(size_t)n * D + c] : 0.0f;
    }
    __syncthreads();
    int lane = threadIdx.x & 63;
    int wid = threadIdx.x >> 6;      // 0..3
    int node = node0 + lane;
    if (node >= N_NODES) return;
    for (int jj = 0; jj < 50; ++jj) {
        int j = wid * 50 + jj;
        float acc = 0.0f;
        #pragma unroll 4
        for (int k = 0; k < D; ++k)
            acc += hs[lane][k] * W[k * D + j];
        m[(size_t)node * D + j] = acc;
    }
}

// ---------------- aggr[dst] += m[src], float4 per thread ----------------
__global__ void scatter_kernel(const float* __restrict__ m,
                               const int* __restrict__ src,
                               const int* __restrict__ dst,
                               float* __restrict__ aggr) {
    int t = blockIdx.x * blockDim.x + threadIdx.x;
    if (t >= N_EDGES * (D / 4)) return;
    int e = t / (D / 4);
    int c = t % (D / 4);
    int s = src[e], d = dst[e];
    const float4 v = *(const float4*)&m[(size_t)s * D + c * 4];
    float* a = &aggr[(size_t)d * D + c * 4];
    unsafeAtomicAdd(a + 0, v.x);
    unsafeAtomicAdd(a + 1, v.y);
    unsafeAtomicAdd(a + 2, v.z);
    unsafeAtomicAdd(a + 3, v.w);
}

// ---------------- fused GRUCell: h = GRU(aggr, h) ----------------
#define GN 32
__global__ __launch_bounds__(256) void gru_kernel(const float* __restrict__ aggr,
                                                  float* __restrict__ h,
                                                  const float* __restrict__ w_ih,
                                                  const float* __restrict__ w_hh,
                                                  const float* __restrict__ b_ih,
                                                  const float* __restrict__ b_hh) {
    __shared__ float as[GN][D + 1];
    __shared__ float hs[GN][D + 1];
    int node0 = blockIdx.x * GN;
    for (int i = threadIdx.x; i < GN * D; i += 256) {
        int r = i / D, c = i % D;
        int n = node0 + r;
        as[r][c] = (n < N_NODES) ? aggr[(size_t)n * D + c] : 0.0f;
        hs[r][c] = (n < N_NODES) ? h[(size_t)n * D + c] : 0.0f;
    }
    __syncthreads();
    int nl = threadIdx.x & 31;        // node within tile
    int jg = threadIdx.x >> 5;        // 0..7
    int node = node0 + nl;
    if (node >= N_NODES) return;
    for (int jj = 0; jj < 25; ++jj) {
        int j = jg * 25 + jj;
        float ir = b_ih[j],         hr = b_hh[j];
        float iz = b_ih[D + j],     hz = b_hh[D + j];
        float in_ = b_ih[2 * D + j], hn = b_hh[2 * D + j];
        const float* wr_i = &w_ih[(size_t)j * D];
        const float* wz_i = &w_ih[(size_t)(D + j) * D];
        const float* wn_i = &w_ih[(size_t)(2 * D + j) * D];
        const float* wr_h = &w_hh[(size_t)j * D];
        const float* wz_h = &w_hh[(size_t)(D + j) * D];
        const float* wn_h = &w_hh[(size_t)(2 * D + j) * D];
        #pragma unroll 2
        for (int k = 0; k < D; ++k) {
            float a = as[nl][k], hv = hs[nl][k];
            ir  += a * wr_i[k];
            iz  += a * wz_i[k];
            in_ += a * wn_i[k];
            hr  += hv * wr_h[k];
            hz  += hv * wz_h[k];
            hn  += hv * wn_h[k];
        }
        float r = 1.0f / (1.0f + expf(-(ir + hr)));
        float z = 1.0f / (1.0f + expf(-(iz + hz)));
        float n = tanhf(in_ + r * hn);
        h[(size_t)node * D + j] = (1.0f - z) * n + z * hs[nl][j];
    }
}

// ---------------- relu + column-max (bits trick, relu >= 0) ----------------
#define POOL_CHUNK 512
__global__ void pool_kernel(const float* __restrict__ h, unsigned int* __restrict__ pooled) {
    int d = threadIdx.x;
    if (d >= D) return;
    int n0 = blockIdx.x * POOL_CHUNK;
    float mx = 0.0f;
    for (int i = 0; i < POOL_CHUNK; ++i) {
        int n = n0 + i;
        if (n >= N_NODES) break;
        float v = h[(size_t)n * D + d];
        v = v > 0.0f ? v : 0.0f;
        mx = v > mx ? v : mx;
    }
    atomicMax(&pooled[d], __float_as_uint(mx));
}

// ---------------- logits + softmax ----------------
__global__ void head_kernel(const unsigned int* __restrict__ pooled,
                            const float* __restrict__ cls_w,
                            const float* __restrict__ cls_b,
                            float* __restrict__ out) {
    if (threadIdx.x == 0) {
        float l0 = cls_b[0], l1 = cls_b[1];
        for (int d = 0; d < D; ++d) {
            float p = __uint_as_float(pooled[d]);
            l0 += p * cls_w[d];
            l1 += p * cls_w[D + d];
        }
        float mx = l0 > l1 ? l0 : l1;
        float e0 = expf(l0 - mx), e1 = expf(l1 - mx);
        out[0] = e0 / (e0 + e1);
        out[1] = e1 / (e0 + e1);
    }
}

extern "C" void kernel_launch(void* const* d_in, const int* in_sizes, int n_in,
                              void* d_out, int out_size, void* d_ws, size_t ws_size,
                              hipStream_t stream) {
    const float* x     = (const float*)d_in[0];
    const float* W     = (const float*)d_in[1];
    const float* w_ih  = (const float*)d_in[2];
    const float* w_hh  = (const float*)d_in[3];
    const float* b_ih  = (const float*)d_in[4];
    const float* b_hh  = (const float*)d_in[5];
    const float* cls_w = (const float*)d_in[6];
    const float* cls_b = (const float*)d_in[7];
    const int*   ei    = (const int*)d_in[8];
    const int* src = ei;
    const int* dst = ei + N_EDGES;

    float* h    = (float*)d_ws;
    float* m    = h + (size_t)N_NODES * D;
    float* aggr = m + (size_t)N_NODES * D;
    unsigned int* pooled = (unsigned int*)(aggr + (size_t)N_NODES * D);

    pad_kernel<<<(N_NODES * D + 255) / 256, 256, 0, stream>>>(x, h);
    for (int s = 0; s < NUM_STEPS; ++s) {
        gemm_hW<<<(N_NODES + TN - 1) / TN, 256, 0, stream>>>(h, W + (size_t)s * D * D, m);
        hipMemsetAsync(aggr, 0, (size_t)N_NODES * D * sizeof(float), stream);
        int nt = N_EDGES * (D / 4);
        scatter_kernel<<<(nt + 255) / 256, 256, 0, stream>>>(m, src, dst, aggr);
        gru_kernel<<<(N_NODES + GN - 1) / GN, 256, 0, stream>>>(aggr, h, w_ih, w_hh, b_ih, b_hh);
    }
    hipMemsetAsync(pooled, 0, D * sizeof(unsigned int), stream);
    pool_kernel<<<(N_NODES + POOL_CHUNK - 1) / POOL_CHUNK, 256, 0, stream>>>(h, pooled);
    head_kernel<<<1, 64, 0, stream>>>(pooled, cls_w, cls_b, (float*)d_out);
}

// Round 2
// 12711.750 us; speedup vs baseline: 2.4972x; 2.4972x over previous
//
#include <hip/hip_runtime.h>
#include <math.h>

#define N_NODES 100000
#define N_EDGES 400000
#define IN_DIM 100
#define D 200
#define NUM_STEPS 4

// Precomputed Wc[s] = w_ih @ W[s]^T : Wc[s][j][k] = sum_t w_ih[j,t] * W[s][k,t]
// so that gi = aggr_raw @ Wc[s]^T(row-major [600][200]) == (aggr_raw@W[s]) @ w_ih^T
__device__ float g_Wc[NUM_STEPS * 600 * 200];

// ---------------- pad: h[:, :100] = x, h[:, 100:] = 0 ----------------
__global__ void pad_kernel(const float* __restrict__ x, float* __restrict__ h) {
    int idx = blockIdx.x * blockDim.x + threadIdx.x;
    if (idx >= N_NODES * D) return;
    int n = idx / D, d = idx % D;
    h[idx] = (d < IN_DIM) ? x[n * IN_DIM + d] : 0.0f;
}

// ---------------- Wc precompute: block=(s*600+j), thread=k ----------------
__global__ __launch_bounds__(256) void wc_kernel(const float* __restrict__ W,
                                                 const float* __restrict__ w_ih) {
    int s = blockIdx.x / 600;
    int j = blockIdx.x % 600;
    int k = threadIdx.x;
    if (k >= D) return;
    const float* wr = &w_ih[(size_t)j * D];          // row j of w_ih  [600,200]
    const float* Wr = &W[(size_t)s * D * D + (size_t)k * D];  // row k of W[s]
    float acc = 0.0f;
    #pragma unroll 4
    for (int t = 0; t < D; ++t) acc += wr[t] * Wr[t];
    g_Wc[(size_t)s * 600 * D + (size_t)j * D + k] = acc;
}

// ---------------- aggr_raw[dst] += h[src], float4 per thread ----------------
__global__ void scatter_kernel(const float* __restrict__ h,
                               const int* __restrict__ src,
                               const int* __restrict__ dst,
                               float* __restrict__ aggr) {
    int t = blockIdx.x * blockDim.x + threadIdx.x;
    if (t >= N_EDGES * (D / 4)) return;
    int e = t / (D / 4);
    int c = t % (D / 4);
    int s = src[e], d = dst[e];
    const float4 v = *(const float4*)&h[(size_t)s * D + c * 4];
    float* a = &aggr[(size_t)d * D + c * 4];
    unsafeAtomicAdd(a + 0, v.x);
    unsafeAtomicAdd(a + 1, v.y);
    unsafeAtomicAdd(a + 2, v.z);
    unsafeAtomicAdd(a + 3, v.w);
}

// ---------------- fused GRU: register-blocked dual GEMM + gates ----------------
// block: 64 nodes x 40 j-cols x 6 gate-slices; 320 threads (5 waves)
// thread: 8 nodes x 1 j x 6 gates = 48 accumulators
#define BM 64
#define BJ 40
#define BK 8
__global__ __launch_bounds__(320) void fused_gru(const float* __restrict__ aggr,
                                                 const float* __restrict__ hcur,
                                                 float* __restrict__ hnext,
                                                 const float* __restrict__ w_hh,
                                                 const float* __restrict__ b_ih,
                                                 const float* __restrict__ b_hh,
                                                 int step) {
    __shared__ float As[BK][BM + 4];   // aggr_raw k-slice (k-major)
    __shared__ float Hs[BK][BM + 4];   // h k-slice
    __shared__ float Bs[BJ][52];       // per j-row: 6 slices x 8 k (48 used)

    const float* Wc = &g_Wc[(size_t)step * 600 * D];
    int m0 = blockIdx.x * BM;
    int j0 = blockIdx.y * BJ;
    int tid = threadIdx.x;
    int jl = tid % BJ;        // j within tile
    int ng = tid / BJ;        // node group 0..7

    float acc[6][8];
    #pragma unroll
    for (int g = 0; g < 6; ++g)
        #pragma unroll
        for (int i = 0; i < 8; ++i) acc[g][i] = 0.0f;

    for (int kt = 0; kt < D; kt += BK) {
        __syncthreads();
        // ---- stage A (aggr) and H (h): 64 rows x 8 k each, 2 float4/row ----
        for (int idx = tid; idx < 256; idx += 320) {
            int which = idx >> 7;            // 0: aggr, 1: h
            int rem = idx & 127;
            int row = rem >> 1, part = rem & 1;
            int n = m0 + row;
            float4 v = make_float4(0.f, 0.f, 0.f, 0.f);
            const float* srcp = which ? hcur : aggr;
            if (n < N_NODES) v = *(const float4*)&srcp[(size_t)n * D + kt + part * 4];
            float* dstc = which ? &Hs[0][0] : &As[0][0];
            dstc[(part * 4 + 0) * (BM + 4) + row] = v.x;
            dstc[(part * 4 + 1) * (BM + 4) + row] = v.y;
            dstc[(part * 4 + 2) * (BM + 4) + row] = v.z;
            dstc[(part * 4 + 3) * (BM + 4) + row] = v.w;
        }
        // ---- stage B: 6 slices x 40 rows x 8 k ----
        for (int idx = tid; idx < 480; idx += 320) {
            int slice = idx / 80;            // 0..5
            int rem = idx % 80;
            int row = rem >> 1, part = rem & 1;
            int jg = j0 + row;               // < 200 always (5*40=200)
            const float* srcp = (slice < 3)
                ? &Wc[(size_t)(slice * D + jg) * D]
                : &w_hh[(size_t)((slice - 3) * D + jg) * D];
            float4 v = *(const float4*)&srcp[kt + part * 4];
            *(float4*)&Bs[row][slice * 8 + part * 4] = v;
        }
        __syncthreads();

        // hoist this thread's 48 B-values into registers
        __attribute__((aligned(16))) float bfrag[48];
        #pragma unroll
        for (int i = 0; i < 12; ++i)
            *(float4*)&bfrag[i * 4] = *(const float4*)&Bs[jl][i * 4];

        #pragma unroll
        for (int k = 0; k < BK; ++k) {
            float4 a0 = *(const float4*)&As[k][ng * 8];
            float4 a1 = *(const float4*)&As[k][ng * 8 + 4];
            float4 h0 = *(const float4*)&Hs[k][ng * 8];
            float4 h1 = *(const float4*)&Hs[k][ng * 8 + 4];
            float av[8] = {a0.x, a0.y, a0.z, a0.w, a1.x, a1.y, a1.z, a1.w};
            float hv[8] = {h0.x, h0.y, h0.z, h0.w, h1.x, h1.y, h1.z, h1.w};
            #pragma unroll
            for (int g = 0; g < 3; ++g) {
                float bi = bfrag[g * 8 + k];
                float bh = bfrag[(g + 3) * 8 + k];
                #pragma unroll
                for (int i = 0; i < 8; ++i) {
                    acc[g][i] += av[i] * bi;
                    acc[g + 3][i] += hv[i] * bh;
                }
            }
        }
    }

    // ---- epilogue: gates + write new h ----
    int j = j0 + jl;
    float bir = b_ih[j], biz = b_ih[D + j], bin = b_ih[2 * D + j];
    float bhr = b_hh[j], bhz = b_hh[D + j], bhn = b_hh[2 * D + j];
    #pragma unroll
    for (int i = 0; i < 8; ++i) {
        int n = m0 + ng * 8 + i;
        if (n < N_NODES) {
            float hold = hcur[(size_t)n * D + j];
            float r = 1.0f / (1.0f + expf(-(acc[0][i] + bir + acc[3][i] + bhr)));
            float z = 1.0f / (1.0f + expf(-(acc[1][i] + biz + acc[4][i] + bhz)));
            float hn = acc[5][i] + bhn;
            float nn = tanhf(acc[2][i] + bin + r * hn);
            hnext[(size_t)n * D + j] = (1.0f - z) * nn + z * hold;
        }
    }
}

// ---------------- relu + column-max (bits trick, relu >= 0) ----------------
#define POOL_CHUNK 512
__global__ void pool_kernel(const float* __restrict__ h, unsigned int* __restrict__ pooled) {
    int d = threadIdx.x;
    if (d >= D) return;
    int n0 = blockIdx.x * POOL_CHUNK;
    float mx = 0.0f;
    for (int i = 0; i < POOL_CHUNK; ++i) {
        int n = n0 + i;
        if (n >= N_NODES) break;
        float v = h[(size_t)n * D + d];
        v = v > 0.0f ? v : 0.0f;
        mx = v > mx ? v : mx;
    }
    atomicMax(&pooled[d], __float_as_uint(mx));
}

// ---------------- logits + softmax ----------------
__global__ void head_kernel(const unsigned int* __restrict__ pooled,
                            const float* __restrict__ cls_w,
                            const float* __restrict__ cls_b,
                            float* __restrict__ out) {
    if (threadIdx.x == 0) {
        float l0 = cls_b[0], l1 = cls_b[1];
        for (int d = 0; d < D; ++d) {
            float p = __uint_as_float(pooled[d]);
            l0 += p * cls_w[d];
            l1 += p * cls_w[D + d];
        }
        float mx = l0 > l1 ? l0 : l1;
        float e0 = expf(l0 - mx), e1 = expf(l1 - mx);
        out[0] = e0 / (e0 + e1);
        out[1] = e1 / (e0 + e1);
    }
}

extern "C" void kernel_launch(void* const* d_in, const int* in_sizes, int n_in,
                              void* d_out, int out_size, void* d_ws, size_t ws_size,
                              hipStream_t stream) {
    const float* x     = (const float*)d_in[0];
    const float* W     = (const float*)d_in[1];
    const float* w_ih  = (const float*)d_in[2];
    const float* w_hh  = (const float*)d_in[3];
    const float* b_ih  = (const float*)d_in[4];
    const float* b_hh  = (const float*)d_in[5];
    const float* cls_w = (const float*)d_in[6];
    const float* cls_b = (const float*)d_in[7];
    const int*   ei    = (const int*)d_in[8];
    const int* src = ei;
    const int* dst = ei + N_EDGES;

    float* hA   = (float*)d_ws;
    float* hB   = hA + (size_t)N_NODES * D;
    float* aggr = hB + (size_t)N_NODES * D;
    unsigned int* pooled = (unsigned int*)(aggr + (size_t)N_NODES * D);

    wc_kernel<<<NUM_STEPS * 600, 256, 0, stream>>>(W, w_ih);
    pad_kernel<<<(N_NODES * D + 255) / 256, 256, 0, stream>>>(x, hA);

    float* hcur = hA;
    float* hnext = hB;
    for (int s = 0; s < NUM_STEPS; ++s) {
        hipMemsetAsync(aggr, 0, (size_t)N_NODES * D * sizeof(float), stream);
        int nt = N_EDGES * (D / 4);
        scatter_kernel<<<(nt + 255) / 256, 256, 0, stream>>>(hcur, src, dst, aggr);
        dim3 grid((N_NODES + BM - 1) / BM, D / BJ);
        fused_gru<<<grid, 320, 0, stream>>>(aggr, hcur, hnext, w_hh, b_ih, b_hh, s);
        float* t = hcur; hcur = hnext; hnext = t;
    }
    hipMemsetAsync(pooled, 0, D * sizeof(unsigned int), stream);
    pool_kernel<<<(N_NODES + POOL_CHUNK - 1) / POOL_CHUNK, 256, 0, stream>>>(hcur, pooled);
    head_kernel<<<1, 64, 0, stream>>>(pooled, cls_w, cls_b, (float*)d_out);
}

// Round 3
// 1497.866 us; speedup vs baseline: 21.1925x; 8.4866x over previous
//
#include <hip/hip_runtime.h>
#include <hip/hip_bf16.h>
#include <math.h>

#define N_NODES 100000
#define N_PAD   100096   // multiple of 256
#define N_EDGES 400000
#define IN_DIM  100
#define D       200
#define DP      208      // j padded to 13*16
#define KP      224      // k padded to 7*32
#define NUM_STEPS 4

typedef __attribute__((ext_vector_type(8))) short bfrag;   // 8 bf16 (4 VGPRs)
typedef __attribute__((ext_vector_type(4))) float facc;    // 4 fp32

// Wc[s] = w_ih @ W[s]^T so that gi = aggr_raw @ Wc[s]^T  (scatter is linear)
__device__ float g_Wc[NUM_STEPS * 600 * D];
// weights in MFMA B-fragment order: [s][gate6][jt13][kt7][lane64][8]
__device__ short g_Wall[NUM_STEPS * 6 * 13 * 7 * 64 * 8];
__device__ float g_bias[6 * DP];

// ---------------- Wc precompute: block=(s*600+j), thread=k ----------------
__global__ __launch_bounds__(256) void wc_kernel(const float* __restrict__ W,
                                                 const float* __restrict__ w_ih) {
    int s = blockIdx.x / 600;
    int j = blockIdx.x % 600;
    int k = threadIdx.x;
    if (k >= D) return;
    const float* wr = &w_ih[(size_t)j * D];
    const float* Wr = &W[(size_t)s * D * D + (size_t)k * D];
    float acc = 0.0f;
    #pragma unroll 4
    for (int t = 0; t < D; ++t) acc += wr[t] * Wr[t];
    g_Wc[((size_t)s * 600 + j) * D + k] = acc;
}

// ---------------- permute weights into B-fragment order (bf16) ----------------
__global__ __launch_bounds__(256) void wconv_kernel(const float* __restrict__ w_hh) {
    int idx = blockIdx.x * 256 + threadIdx.x;           // < 4*6*13*7*64 = 139776
    int l  = idx & 63;
    int t  = (idx >> 6) % 7;
    int jt = (idx / (64 * 7)) % 13;
    int g  = (idx / (64 * 7 * 13)) % 6;
    int s  = idx / (64 * 7 * 13 * 6);
    int j  = jt * 16 + (l & 15);
    int k0 = t * 32 + (l >> 4) * 8;
    short* out = g_Wall + (size_t)idx * 8;
    #pragma unroll
    for (int i = 0; i < 8; ++i) {
        int k = k0 + i;
        float v = 0.0f;
        if (j < D && k < D)
            v = (g < 3) ? g_Wc[((size_t)s * 600 + g * 200 + j) * D + k]
                        : w_hh[((size_t)(g - 3) * 200 + j) * D + k];
        __hip_bfloat16 b = __float2bfloat16(v);
        out[i] = *reinterpret_cast<short*>(&b);
    }
}

__global__ void bias_kernel(const float* __restrict__ b_ih, const float* __restrict__ b_hh) {
    int idx = blockIdx.x * 256 + threadIdx.x;
    if (idx >= 6 * DP) return;
    int g = idx / DP, j = idx % DP;
    float v = 0.0f;
    if (j < D) v = (g < 3) ? b_ih[g * 200 + j] : b_hh[(g - 3) * 200 + j];
    g_bias[idx] = v;
}

// ---------------- pad: h[:, :100] = bf16(x), rest 0 ----------------
__global__ void pad_kernel(const float* __restrict__ x, __hip_bfloat16* __restrict__ h) {
    int idx = blockIdx.x * 256 + threadIdx.x;   // N_PAD*KP exact multiple of 256
    int n = idx / KP, c = idx % KP;
    float v = (n < N_NODES && c < IN_DIM) ? x[n * IN_DIM + c] : 0.0f;
    h[idx] = __float2bfloat16(v);
}

// ---------------- CSR build ----------------
__global__ void count_kernel(const int* __restrict__ dst, int* __restrict__ cnt) {
    int e = blockIdx.x * blockDim.x + threadIdx.x;
    if (e < N_EDGES) atomicAdd(&cnt[dst[e]], 1);
}

#define SCAN_B 1024
__global__ __launch_bounds__(SCAN_B) void scan1(const int* __restrict__ cnt,
                                                int* __restrict__ incl, int* __restrict__ bsum) {
    __shared__ int sh[SCAN_B];
    int i = blockIdx.x * SCAN_B + threadIdx.x;
    int v = (i < N_NODES) ? cnt[i] : 0;
    sh[threadIdx.x] = v; __syncthreads();
    for (int off = 1; off < SCAN_B; off <<= 1) {
        int t = (threadIdx.x >= off) ? sh[threadIdx.x - off] : 0;
        __syncthreads();
        sh[threadIdx.x] += t;
        __syncthreads();
    }
    if (i < N_NODES) incl[i] = sh[threadIdx.x];
    if (threadIdx.x == SCAN_B - 1) bsum[blockIdx.x] = sh[threadIdx.x];
}
__global__ void scan2(int* __restrict__ bsum, int nb) {
    __shared__ int sh[128];
    int v = (threadIdx.x < nb) ? bsum[threadIdx.x] : 0;
    sh[threadIdx.x] = v; __syncthreads();
    for (int off = 1; off < 128; off <<= 1) {
        int t = (threadIdx.x >= off) ? sh[threadIdx.x - off] : 0;
        __syncthreads();
        sh[threadIdx.x] += t;
        __syncthreads();
    }
    if (threadIdx.x < nb) bsum[threadIdx.x] = sh[threadIdx.x] - v;  // exclusive
}
__global__ void scan3(const int* __restrict__ cnt, const int* __restrict__ incl,
                      const int* __restrict__ bsum, int* __restrict__ off,
                      int* __restrict__ cursor) {
    int i = blockIdx.x * blockDim.x + threadIdx.x;
    if (i < N_NODES) {
        int v = incl[i] - cnt[i] + bsum[i / SCAN_B];
        off[i] = v; cursor[i] = v;
    }
    if (i == 0) off[N_NODES] = N_EDGES;
}
__global__ void fill_kernel(const int* __restrict__ src, const int* __restrict__ dst,
                            int* __restrict__ cursor, int* __restrict__ esrc) {
    int e = blockIdx.x * blockDim.x + threadIdx.x;
    if (e < N_EDGES) {
        int pos = atomicAdd(&cursor[dst[e]], 1);
        esrc[pos] = src[e];
    }
}

// ---------------- gather: aggr[n] = sum over in-edges of h[src] ----------------
__global__ __launch_bounds__(256) void gather_kernel(const __hip_bfloat16* __restrict__ h,
                                                     const int* __restrict__ off,
                                                     const int* __restrict__ esrc,
                                                     __hip_bfloat16* __restrict__ aggr) {
    int wave = threadIdx.x >> 6, lane = threadIdx.x & 63;
    int n = blockIdx.x * 4 + wave;
    if (n >= N_PAD) return;
    float a0 = 0, a1 = 0, a2 = 0, a3 = 0;
    int c3 = lane + 192;
    if (n < N_NODES) {
        int e0 = off[n], e1 = off[n + 1];
        for (int e = e0; e < e1; ++e) {
            const __hip_bfloat16* row = h + (size_t)esrc[e] * KP;
            a0 += __bfloat162float(row[lane]);
            a1 += __bfloat162float(row[lane + 64]);
            a2 += __bfloat162float(row[lane + 128]);
            if (c3 < D) a3 += __bfloat162float(row[c3]);
        }
    }
    __hip_bfloat16* out = aggr + (size_t)n * KP;
    out[lane]       = __float2bfloat16(a0);
    out[lane + 64]  = __float2bfloat16(a1);
    out[lane + 128] = __float2bfloat16(a2);
    out[c3]         = __float2bfloat16(c3 < D ? a3 : 0.0f);
}

// ---------------- MFMA GRU: both GEMMs + gates fused ----------------
// grid (13 j-tiles, N_PAD/256); block 256 = 4 waves; wave: 64 M x 16 j x 6 gates
__global__ __launch_bounds__(256, 2) void gru_mfma(const __hip_bfloat16* __restrict__ aggr,
                                                   const __hip_bfloat16* __restrict__ hcur,
                                                   __hip_bfloat16* __restrict__ hnext,
                                                   int step) {
    __shared__ short Bs[6 * 7 * 64 * 8];   // 42 KB, fragment-ordered
    int tid = threadIdx.x;
    int jt = blockIdx.x;
    int mblk = blockIdx.y * 256;

    const short* Wbase = g_Wall + (size_t)step * (6 * 13 * 7 * 64 * 8);
    for (int c = tid; c < 6 * 7 * 64; c += 256) {
        int g = c / 448, rem = c % 448;
        *(bfrag*)&Bs[(size_t)c * 8] =
            *(const bfrag*)(Wbase + ((size_t)(g * 13 + jt) * 448 + rem) * 8);
    }
    __syncthreads();

    int lane = tid & 63, wave = tid >> 6;
    int mw = mblk + wave * 64;
    int mrow = lane & 15, kq = lane >> 4;
    size_t abase = (size_t)(mw + mrow) * KP + kq * 8;

    facc acc[6][4];
    #pragma unroll
    for (int g = 0; g < 6; ++g)
        #pragma unroll
        for (int mf = 0; mf < 4; ++mf) acc[g][mf] = (facc)(0.0f);

    for (int t = 0; t < 7; ++t) {
        bfrag av[4], hv[4], bv[6];
        #pragma unroll
        for (int mf = 0; mf < 4; ++mf) {
            av[mf] = *(const bfrag*)(aggr + abase + mf * 16 * KP + t * 32);
            hv[mf] = *(const bfrag*)(hcur + abase + mf * 16 * KP + t * 32);
        }
        #pragma unroll
        for (int g = 0; g < 6; ++g)
            bv[g] = *(const bfrag*)&Bs[((g * 7 + t) * 64 + lane) * 8];
        #pragma unroll
        for (int g = 0; g < 3; ++g)
            #pragma unroll
            for (int mf = 0; mf < 4; ++mf) {
                acc[g][mf] = __builtin_amdgcn_mfma_f32_16x16x32_bf16(av[mf], bv[g], acc[g][mf], 0, 0, 0);
                acc[g + 3][mf] = __builtin_amdgcn_mfma_f32_16x16x32_bf16(hv[mf], bv[g + 3], acc[g + 3][mf], 0, 0, 0);
            }
    }

    // epilogue: C/D layout col=lane&15 (j), row=(lane>>4)*4+reg (m)
    int j = jt * 16 + (lane & 15);
    int rowq = (lane >> 4) * 4;
    bool jok = (j < D);
    float bir = g_bias[j],          biz = g_bias[DP + j],     bin = g_bias[2 * DP + j];
    float bhr = g_bias[3 * DP + j], bhz = g_bias[4 * DP + j], bhn = g_bias[5 * DP + j];
    #pragma unroll
    for (int mf = 0; mf < 4; ++mf) {
        int m0 = mw + mf * 16 + rowq;
        #pragma unroll
        for (int r = 0; r < 4; ++r) {
            int m = m0 + r;
            if (jok && m < N_NODES) {
                float hold = __bfloat162float(hcur[(size_t)m * KP + j]);
                float rr = 1.0f / (1.0f + expf(-(acc[0][mf][r] + bir + acc[3][mf][r] + bhr)));
                float zz = 1.0f / (1.0f + expf(-(acc[1][mf][r] + biz + acc[4][mf][r] + bhz)));
                float nn = tanhf(acc[2][mf][r] + bin + rr * (acc[5][mf][r] + bhn));
                hnext[(size_t)m * KP + j] = __float2bfloat16((1.0f - zz) * nn + zz * hold);
            }
        }
    }
}

// ---------------- relu + column-max (bits trick, relu >= 0) ----------------
#define POOL_CHUNK 512
__global__ void pool_kernel(const __hip_bfloat16* __restrict__ h, unsigned int* __restrict__ pooled) {
    int d = threadIdx.x;
    if (d >= D) return;
    int n0 = blockIdx.x * POOL_CHUNK;
    float mx = 0.0f;
    for (int i = 0; i < POOL_CHUNK; ++i) {
        int n = n0 + i;
        if (n >= N_NODES) break;
        float v = __bfloat162float(h[(size_t)n * KP + d]);
        v = v > 0.0f ? v : 0.0f;
        mx = v > mx ? v : mx;
    }
    atomicMax(&pooled[d], __float_as_uint(mx));
}

// ---------------- logits + softmax ----------------
__global__ void head_kernel(const unsigned int* __restrict__ pooled,
                            const float* __restrict__ cls_w,
                            const float* __restrict__ cls_b,
                            float* __restrict__ out) {
    if (threadIdx.x == 0) {
        float l0 = cls_b[0], l1 = cls_b[1];
        for (int d = 0; d < D; ++d) {
            float p = __uint_as_float(pooled[d]);
            l0 += p * cls_w[d];
            l1 += p * cls_w[D + d];
        }
        float mx = l0 > l1 ? l0 : l1;
        float e0 = expf(l0 - mx), e1 = expf(l1 - mx);
        out[0] = e0 / (e0 + e1);
        out[1] = e1 / (e0 + e1);
    }
}

extern "C" void kernel_launch(void* const* d_in, const int* in_sizes, int n_in,
                              void* d_out, int out_size, void* d_ws, size_t ws_size,
                              hipStream_t stream) {
    const float* x     = (const float*)d_in[0];
    const float* W     = (const float*)d_in[1];
    const float* w_ih  = (const float*)d_in[2];
    const float* w_hh  = (const float*)d_in[3];
    const float* b_ih  = (const float*)d_in[4];
    const float* b_hh  = (const float*)d_in[5];
    const float* cls_w = (const float*)d_in[6];
    const float* cls_b = (const float*)d_in[7];
    const int*   ei    = (const int*)d_in[8];
    const int* src = ei;
    const int* dst = ei + N_EDGES;

    const size_t ROWB = (size_t)N_PAD * KP;     // bf16 elements per buffer
    __hip_bfloat16* hA   = (__hip_bfloat16*)d_ws;
    __hip_bfloat16* hB   = hA + ROWB;
    __hip_bfloat16* aggr = hB + ROWB;
    int* cnt    = (int*)(aggr + ROWB);
    int* incl   = cnt + N_NODES;
    int* bsum   = incl + N_NODES;
    int* off    = bsum + 128;
    int* cursor = off + N_NODES + 1;
    int* esrc   = cursor + N_NODES;
    unsigned int* pooled = (unsigned int*)(esrc + N_EDGES);

    // CSR build (once per call; edges are step-invariant)
    hipMemsetAsync(cnt, 0, N_NODES * sizeof(int), stream);
    count_kernel<<<(N_EDGES + 255) / 256, 256, 0, stream>>>(dst, cnt);
    scan1<<<(N_NODES + SCAN_B - 1) / SCAN_B, SCAN_B, 0, stream>>>(cnt, incl, bsum);
    scan2<<<1, 128, 0, stream>>>(bsum, (N_NODES + SCAN_B - 1) / SCAN_B);
    scan3<<<(N_NODES + 255) / 256, 256, 0, stream>>>(cnt, incl, bsum, off, cursor);
    fill_kernel<<<(N_EDGES + 255) / 256, 256, 0, stream>>>(src, dst, cursor, esrc);

    // weight prep
    wc_kernel<<<NUM_STEPS * 600, 256, 0, stream>>>(W, w_ih);
    wconv_kernel<<<(NUM_STEPS * 6 * 13 * 7 * 64) / 256, 256, 0, stream>>>(w_hh);
    bias_kernel<<<(6 * DP + 255) / 256, 256, 0, stream>>>(b_ih, b_hh);

    pad_kernel<<<(int)(ROWB / 256), 256, 0, stream>>>(x, hA);

    __hip_bfloat16* hcur = hA;
    __hip_bfloat16* hnext = hB;
    for (int s = 0; s < NUM_STEPS; ++s) {
        gather_kernel<<<N_PAD / 4, 256, 0, stream>>>(hcur, off, esrc, aggr);
        dim3 grid(13, N_PAD / 256);
        gru_mfma<<<grid, 256, 0, stream>>>(aggr, hcur, hnext, s);
        __hip_bfloat16* t = hcur; hcur = hnext; hnext = t;
    }
    hipMemsetAsync(pooled, 0, D * sizeof(unsigned int), stream);
    pool_kernel<<<(N_NODES + POOL_CHUNK - 1) / POOL_CHUNK, 256, 0, stream>>>(hcur, pooled);
    head_kernel<<<1, 64, 0, stream>>>(pooled, cls_w, cls_b, (float*)d_out);
}

// Round 4
// 1306.020 us; speedup vs baseline: 24.3056x; 1.1469x over previous
//
#include <hip/hip_runtime.h>
#include <hip/hip_bf16.h>
#include <math.h>

#define N_NODES 100000
#define N_PAD   100096   // multiple of 256
#define N_EDGES 400000
#define IN_DIM  100
#define D       200
#define DP      208      // j padded to 13*16
#define KP      224      // k padded to 7*32
#define NUM_STEPS 4

typedef __attribute__((ext_vector_type(8))) short bfrag;   // 8 bf16 (4 VGPRs)
typedef __attribute__((ext_vector_type(4))) float facc;    // 4 fp32

// Wc[s] = w_ih @ W[s]^T so that gi = aggr_raw @ Wc[s]^T  (scatter is linear)
__device__ float g_Wc[NUM_STEPS * 600 * D];
// weights in MFMA B-fragment order: [s][gate6][jt13][kt7][lane64][8]
__device__ short g_Wall[NUM_STEPS * 6 * 13 * 7 * 64 * 8];
__device__ float g_bias[6 * DP];

__device__ __forceinline__ float fast_sigmoid(float x) {
    return __builtin_amdgcn_rcpf(1.0f + __expf(-x));
}
__device__ __forceinline__ float fast_tanh(float x) {
    return 2.0f * __builtin_amdgcn_rcpf(1.0f + __expf(-2.0f * x)) - 1.0f;
}

// ---------------- Wc precompute: block=(s*600+j), thread=k ----------------
__global__ __launch_bounds__(256) void wc_kernel(const float* __restrict__ W,
                                                 const float* __restrict__ w_ih) {
    int s = blockIdx.x / 600;
    int j = blockIdx.x % 600;
    int k = threadIdx.x;
    if (k >= D) return;
    const float* wr = &w_ih[(size_t)j * D];
    const float* Wr = &W[(size_t)s * D * D + (size_t)k * D];
    float acc = 0.0f;
    #pragma unroll 4
    for (int t = 0; t < D; ++t) acc += wr[t] * Wr[t];
    g_Wc[((size_t)s * 600 + j) * D + k] = acc;
}

// ---------------- permute weights into B-fragment order (bf16) ----------------
__global__ __launch_bounds__(256) void wconv_kernel(const float* __restrict__ w_hh) {
    int idx = blockIdx.x * 256 + threadIdx.x;           // < 4*6*13*7*64 = 139776
    int l  = idx & 63;
    int t  = (idx >> 6) % 7;
    int jt = (idx / (64 * 7)) % 13;
    int g  = (idx / (64 * 7 * 13)) % 6;
    int s  = idx / (64 * 7 * 13 * 6);
    int j  = jt * 16 + (l & 15);
    int k0 = t * 32 + (l >> 4) * 8;
    short* out = g_Wall + (size_t)idx * 8;
    #pragma unroll
    for (int i = 0; i < 8; ++i) {
        int k = k0 + i;
        float v = 0.0f;
        if (j < D && k < D)
            v = (g < 3) ? g_Wc[((size_t)s * 600 + g * 200 + j) * D + k]
                        : w_hh[((size_t)(g - 3) * 200 + j) * D + k];
        __hip_bfloat16 b = __float2bfloat16(v);
        out[i] = *reinterpret_cast<short*>(&b);
    }
}

__global__ void bias_kernel(const float* __restrict__ b_ih, const float* __restrict__ b_hh) {
    int idx = blockIdx.x * 256 + threadIdx.x;
    if (idx >= 6 * DP) return;
    int g = idx / DP, j = idx % DP;
    float v = 0.0f;
    if (j < D) v = (g < 3) ? b_ih[g * 200 + j] : b_hh[(g - 3) * 200 + j];
    g_bias[idx] = v;
}

// ---------------- pad: h[:, :100] = bf16(x), rest 0 ----------------
__global__ void pad_kernel(const float* __restrict__ x, __hip_bfloat16* __restrict__ h) {
    int idx = blockIdx.x * 256 + threadIdx.x;   // N_PAD*KP exact multiple of 256
    int n = idx / KP, c = idx % KP;
    float v = (n < N_NODES && c < IN_DIM) ? x[n * IN_DIM + c] : 0.0f;
    h[idx] = __float2bfloat16(v);
}

// ---------------- CSR build ----------------
__global__ void count_kernel(const int* __restrict__ dst, int* __restrict__ cnt) {
    int e = blockIdx.x * blockDim.x + threadIdx.x;
    if (e < N_EDGES) atomicAdd(&cnt[dst[e]], 1);
}

#define SCAN_B 1024
__global__ __launch_bounds__(SCAN_B) void scan1(const int* __restrict__ cnt,
                                                int* __restrict__ incl, int* __restrict__ bsum) {
    __shared__ int sh[SCAN_B];
    int i = blockIdx.x * SCAN_B + threadIdx.x;
    int v = (i < N_NODES) ? cnt[i] : 0;
    sh[threadIdx.x] = v; __syncthreads();
    for (int off = 1; off < SCAN_B; off <<= 1) {
        int t = (threadIdx.x >= off) ? sh[threadIdx.x - off] : 0;
        __syncthreads();
        sh[threadIdx.x] += t;
        __syncthreads();
    }
    if (i < N_NODES) incl[i] = sh[threadIdx.x];
    if (threadIdx.x == SCAN_B - 1) bsum[blockIdx.x] = sh[threadIdx.x];
}
__global__ void scan2(int* __restrict__ bsum, int nb) {
    __shared__ int sh[128];
    int v = (threadIdx.x < nb) ? bsum[threadIdx.x] : 0;
    sh[threadIdx.x] = v; __syncthreads();
    for (int off = 1; off < 128; off <<= 1) {
        int t = (threadIdx.x >= off) ? sh[threadIdx.x - off] : 0;
        __syncthreads();
        sh[threadIdx.x] += t;
        __syncthreads();
    }
    if (threadIdx.x < nb) bsum[threadIdx.x] = sh[threadIdx.x] - v;  // exclusive
}
__global__ void scan3(const int* __restrict__ cnt, const int* __restrict__ incl,
                      const int* __restrict__ bsum, int* __restrict__ off,
                      int* __restrict__ cursor) {
    int i = blockIdx.x * blockDim.x + threadIdx.x;
    if (i < N_NODES) {
        int v = incl[i] - cnt[i] + bsum[i / SCAN_B];
        off[i] = v; cursor[i] = v;
    }
    if (i == 0) off[N_NODES] = N_EDGES;
}
__global__ void fill_kernel(const int* __restrict__ src, const int* __restrict__ dst,
                            int* __restrict__ cursor, int* __restrict__ esrc) {
    int e = blockIdx.x * blockDim.x + threadIdx.x;
    if (e < N_EDGES) {
        int pos = atomicAdd(&cursor[dst[e]], 1);
        esrc[pos] = src[e];
    }
}

// ---------------- gather: aggr[n] = sum over in-edges of h[src] ----------------
// wave per node; lane < 56 handles 4 cols (8B ushort4); cols >= 200 forced zero
__global__ __launch_bounds__(256) void gather_kernel(const __hip_bfloat16* __restrict__ h,
                                                     const int* __restrict__ off,
                                                     const int* __restrict__ esrc,
                                                     __hip_bfloat16* __restrict__ aggr) {
    int wave = threadIdx.x >> 6, lane = threadIdx.x & 63;
    int n = blockIdx.x * 4 + wave;
    if (n >= N_PAD) return;
    int col = lane * 4;
    bool store_l = (lane < 56);
    bool sum_l   = (col < D);     // lanes 0..49
    float a0 = 0, a1 = 0, a2 = 0, a3 = 0;
    if (n < N_NODES && sum_l) {
        int e0 = off[n], e1 = off[n + 1];
        for (int e = e0; e < e1; ++e) {
            const ushort4 v = *(const ushort4*)(h + (size_t)esrc[e] * KP + col);
            a0 += __bfloat162float(*(const __hip_bfloat16*)&v.x);
            a1 += __bfloat162float(*(const __hip_bfloat16*)&v.y);
            a2 += __bfloat162float(*(const __hip_bfloat16*)&v.z);
            a3 += __bfloat162float(*(const __hip_bfloat16*)&v.w);
        }
    }
    if (store_l) {
        __hip_bfloat16 o[4];
        o[0] = __float2bfloat16(a0); o[1] = __float2bfloat16(a1);
        o[2] = __float2bfloat16(a2); o[3] = __float2bfloat16(a3);
        *(ushort4*)(aggr + (size_t)n * KP + col) = *(const ushort4*)o;
    }
}

// ---------------- MFMA GRU: A/H in registers, j-tile loop inside ----------------
// grid N_PAD/128; block 256 = 4 waves; wave: 32 rows, sweeps 13 j-tiles x 6 gates
__global__ __launch_bounds__(256, 2) void gru_mfma(const __hip_bfloat16* __restrict__ aggr,
                                                   const __hip_bfloat16* __restrict__ hcur,
                                                   __hip_bfloat16* __restrict__ hnext,
                                                   int step) {
    int tid = threadIdx.x;
    int lane = tid & 63, wave = tid >> 6;
    int mw = blockIdx.x * 128 + wave * 32;
    int mrow = lane & 15, kq = lane >> 4;
    size_t abase = (size_t)(mw + mrow) * KP + kq * 8;

    // load this wave's A/H fragments once (32 rows x 224 cols each)
    bfrag av[2][7], hv[2][7];
    #pragma unroll
    for (int mf = 0; mf < 2; ++mf)
        #pragma unroll
        for (int t = 0; t < 7; ++t) {
            av[mf][t] = *(const bfrag*)(aggr + abase + mf * 16 * KP + t * 32);
            hv[mf][t] = *(const bfrag*)(hcur + abase + mf * 16 * KP + t * 32);
        }

    const short* Wl = g_Wall + (size_t)step * (6 * 13 * 7 * 64 * 8) + (size_t)lane * 8;
    int jcol = lane & 15;
    int rowq = (lane >> 4) * 4;

    for (int jt = 0; jt < 13; ++jt) {
        facc acc[6][2];
        #pragma unroll
        for (int g = 0; g < 6; ++g)
            #pragma unroll
            for (int mf = 0; mf < 2; ++mf) acc[g][mf] = (facc)(0.0f);

        #pragma unroll
        for (int t = 0; t < 7; ++t) {
            bfrag bv[6];
            #pragma unroll
            for (int g = 0; g < 6; ++g)
                bv[g] = *(const bfrag*)(Wl + (size_t)(((g * 13 + jt) * 7) + t) * 512);
            #pragma unroll
            for (int g = 0; g < 3; ++g)
                #pragma unroll
                for (int mf = 0; mf < 2; ++mf) {
                    acc[g][mf]     = __builtin_amdgcn_mfma_f32_16x16x32_bf16(av[mf][t], bv[g],     acc[g][mf],     0, 0, 0);
                    acc[g + 3][mf] = __builtin_amdgcn_mfma_f32_16x16x32_bf16(hv[mf][t], bv[g + 3], acc[g + 3][mf], 0, 0, 0);
                }
        }

        // epilogue: C/D layout col=lane&15 (j), row=(lane>>4)*4+reg (m)
        int j = jt * 16 + jcol;
        if (j < D) {
            float bir = g_bias[j],          biz = g_bias[DP + j],     bin = g_bias[2 * DP + j];
            float bhr = g_bias[3 * DP + j], bhz = g_bias[4 * DP + j], bhn = g_bias[5 * DP + j];
            #pragma unroll
            for (int mf = 0; mf < 2; ++mf) {
                int m0 = mw + mf * 16 + rowq;
                #pragma unroll
                for (int r = 0; r < 4; ++r) {
                    int m = m0 + r;
                    if (m < N_NODES) {
                        float hold = __bfloat162float(hcur[(size_t)m * KP + j]);
                        float rr = fast_sigmoid(acc[0][mf][r] + bir + acc[3][mf][r] + bhr);
                        float zz = fast_sigmoid(acc[1][mf][r] + biz + acc[4][mf][r] + bhz);
                        float nn = fast_tanh(acc[2][mf][r] + bin + rr * (acc[5][mf][r] + bhn));
                        hnext[(size_t)m * KP + j] = __float2bfloat16((1.0f - zz) * nn + zz * hold);
                    }
                }
            }
        }
    }
}

// ---------------- relu + column-max (bits trick, relu >= 0) ----------------
#define POOL_CHUNK 512
__global__ void pool_kernel(const __hip_bfloat16* __restrict__ h, unsigned int* __restrict__ pooled) {
    int d = threadIdx.x;
    if (d >= D) return;
    int n0 = blockIdx.x * POOL_CHUNK;
    float mx = 0.0f;
    for (int i = 0; i < POOL_CHUNK; ++i) {
        int n = n0 + i;
        if (n >= N_NODES) break;
        float v = __bfloat162float(h[(size_t)n * KP + d]);
        v = v > 0.0f ? v : 0.0f;
        mx = v > mx ? v : mx;
    }
    atomicMax(&pooled[d], __float_as_uint(mx));
}

// ---------------- logits + softmax ----------------
__global__ void head_kernel(const unsigned int* __restrict__ pooled,
                            const float* __restrict__ cls_w,
                            const float* __restrict__ cls_b,
                            float* __restrict__ out) {
    if (threadIdx.x == 0) {
        float l0 = cls_b[0], l1 = cls_b[1];
        for (int d = 0; d < D; ++d) {
            float p = __uint_as_float(pooled[d]);
            l0 += p * cls_w[d];
            l1 += p * cls_w[D + d];
        }
        float mx = l0 > l1 ? l0 : l1;
        float e0 = expf(l0 - mx), e1 = expf(l1 - mx);
        out[0] = e0 / (e0 + e1);
        out[1] = e1 / (e0 + e1);
    }
}

extern "C" void kernel_launch(void* const* d_in, const int* in_sizes, int n_in,
                              void* d_out, int out_size, void* d_ws, size_t ws_size,
                              hipStream_t stream) {
    const float* x     = (const float*)d_in[0];
    const float* W     = (const float*)d_in[1];
    const float* w_ih  = (const float*)d_in[2];
    const float* w_hh  = (const float*)d_in[3];
    const float* b_ih  = (const float*)d_in[4];
    const float* b_hh  = (const float*)d_in[5];
    const float* cls_w = (const float*)d_in[6];
    const float* cls_b = (const float*)d_in[7];
    const int*   ei    = (const int*)d_in[8];
    const int* src = ei;
    const int* dst = ei + N_EDGES;

    const size_t ROWB = (size_t)N_PAD * KP;     // bf16 elements per buffer
    __hip_bfloat16* hA   = (__hip_bfloat16*)d_ws;
    __hip_bfloat16* hB   = hA + ROWB;
    __hip_bfloat16* aggr = hB + ROWB;
    int* cnt    = (int*)(aggr + ROWB);
    int* incl   = cnt + N_NODES;
    int* bsum   = incl + N_NODES;
    int* off    = bsum + 128;
    int* cursor = off + N_NODES + 1;
    int* esrc   = cursor + N_NODES;
    unsigned int* pooled = (unsigned int*)(esrc + N_EDGES);

    // CSR build (once per call; edges are step-invariant)
    hipMemsetAsync(cnt, 0, N_NODES * sizeof(int), stream);
    count_kernel<<<(N_EDGES + 255) / 256, 256, 0, stream>>>(dst, cnt);
    scan1<<<(N_NODES + SCAN_B - 1) / SCAN_B, SCAN_B, 0, stream>>>(cnt, incl, bsum);
    scan2<<<1, 128, 0, stream>>>(bsum, (N_NODES + SCAN_B - 1) / SCAN_B);
    scan3<<<(N_NODES + 255) / 256, 256, 0, stream>>>(cnt, incl, bsum, off, cursor);
    fill_kernel<<<(N_EDGES + 255) / 256, 256, 0, stream>>>(src, dst, cursor, esrc);

    // weight prep
    wc_kernel<<<NUM_STEPS * 600, 256, 0, stream>>>(W, w_ih);
    wconv_kernel<<<(NUM_STEPS * 6 * 13 * 7 * 64) / 256, 256, 0, stream>>>(w_hh);
    bias_kernel<<<(6 * DP + 255) / 256, 256, 0, stream>>>(b_ih, b_hh);

    pad_kernel<<<(int)(ROWB / 256), 256, 0, stream>>>(x, hA);

    __hip_bfloat16* hcur = hA;
    __hip_bfloat16* hnext = hB;
    for (int s = 0; s < NUM_STEPS; ++s) {
        gather_kernel<<<N_PAD / 4, 256, 0, stream>>>(hcur, off, esrc, aggr);
        gru_mfma<<<N_PAD / 128, 256, 0, stream>>>(aggr, hcur, hnext, s);
        __hip_bfloat16* t = hcur; hcur = hnext; hnext = t;
    }
    hipMemsetAsync(pooled, 0, D * sizeof(unsigned int), stream);
    pool_kernel<<<(N_NODES + POOL_CHUNK - 1) / POOL_CHUNK, 256, 0, stream>>>(hcur, pooled);
    head_kernel<<<1, 64, 0, stream>>>(pooled, cls_w, cls_b, (float*)d_out);
}

// Round 5
// 1220.589 us; speedup vs baseline: 26.0068x; 1.0700x over previous
//
#include <hip/hip_runtime.h>
#include <hip/hip_bf16.h>
#include <math.h>

#define N_NODES 100000
#define N_PAD   100096   // multiple of 256
#define N_EDGES 400000
#define IN_DIM  100
#define D       200
#define DP      208      // j padded to 13*16
#define KP      224      // k padded to 7*32
#define NUM_STEPS 4

typedef __attribute__((ext_vector_type(8))) short bfrag;   // 8 bf16 (4 VGPRs)
typedef __attribute__((ext_vector_type(4))) float facc;    // 4 fp32

// Wc[s] = w_ih @ W[s]^T so that gi = aggr_raw @ Wc[s]^T  (scatter is linear)
__device__ float g_Wc[NUM_STEPS * 600 * D];
// weights in MFMA B-fragment order: [s][gate6][jt13][kt7][lane64][8]
__device__ short g_Wall[NUM_STEPS * 6 * 13 * 7 * 64 * 8];
__device__ float g_bias[6 * DP];

__device__ __forceinline__ float fast_sigmoid(float x) {
    return __builtin_amdgcn_rcpf(1.0f + __expf(-x));
}
__device__ __forceinline__ float fast_tanh(float x) {
    return 2.0f * __builtin_amdgcn_rcpf(1.0f + __expf(-2.0f * x)) - 1.0f;
}

// ---------------- Wc precompute: block=(s*600+j), thread=k ----------------
__global__ __launch_bounds__(256) void wc_kernel(const float* __restrict__ W,
                                                 const float* __restrict__ w_ih) {
    int s = blockIdx.x / 600;
    int j = blockIdx.x % 600;
    int k = threadIdx.x;
    if (k >= D) return;
    const float* wr = &w_ih[(size_t)j * D];
    const float* Wr = &W[(size_t)s * D * D + (size_t)k * D];
    float acc = 0.0f;
    #pragma unroll 4
    for (int t = 0; t < D; ++t) acc += wr[t] * Wr[t];
    g_Wc[((size_t)s * 600 + j) * D + k] = acc;
}

// ---------------- permute weights into B-fragment order (bf16) ----------------
__global__ __launch_bounds__(256) void wconv_kernel(const float* __restrict__ w_hh) {
    int idx = blockIdx.x * 256 + threadIdx.x;           // < 4*6*13*7*64 = 139776
    int l  = idx & 63;
    int t  = (idx >> 6) % 7;
    int jt = (idx / (64 * 7)) % 13;
    int g  = (idx / (64 * 7 * 13)) % 6;
    int s  = idx / (64 * 7 * 13 * 6);
    int j  = jt * 16 + (l & 15);
    int k0 = t * 32 + (l >> 4) * 8;
    short* out = g_Wall + (size_t)idx * 8;
    #pragma unroll
    for (int i = 0; i < 8; ++i) {
        int k = k0 + i;
        float v = 0.0f;
        if (j < D && k < D)
            v = (g < 3) ? g_Wc[((size_t)s * 600 + g * 200 + j) * D + k]
                        : w_hh[((size_t)(g - 3) * 200 + j) * D + k];
        __hip_bfloat16 b = __float2bfloat16(v);
        out[i] = *reinterpret_cast<short*>(&b);
    }
}

__global__ void bias_kernel(const float* __restrict__ b_ih, const float* __restrict__ b_hh) {
    int idx = blockIdx.x * 256 + threadIdx.x;
    if (idx >= 6 * DP) return;
    int g = idx / DP, j = idx % DP;
    float v = 0.0f;
    if (j < D) v = (g < 3) ? b_ih[g * 200 + j] : b_hh[(g - 3) * 200 + j];
    g_bias[idx] = v;
}

// ---------------- pad: h[:, :100] = bf16(x), rest 0 ----------------
__global__ void pad_kernel(const float* __restrict__ x, __hip_bfloat16* __restrict__ h) {
    int idx = blockIdx.x * 256 + threadIdx.x;   // N_PAD*KP exact multiple of 256
    int n = idx / KP, c = idx % KP;
    float v = (n < N_NODES && c < IN_DIM) ? x[n * IN_DIM + c] : 0.0f;
    h[idx] = __float2bfloat16(v);
}

// ---------------- CSR build ----------------
__global__ void count_kernel(const int* __restrict__ dst, int* __restrict__ cnt) {
    int e = blockIdx.x * blockDim.x + threadIdx.x;
    if (e < N_EDGES) atomicAdd(&cnt[dst[e]], 1);
}

#define SCAN_B 1024
__global__ __launch_bounds__(SCAN_B) void scan1(const int* __restrict__ cnt,
                                                int* __restrict__ incl, int* __restrict__ bsum) {
    __shared__ int sh[SCAN_B];
    int i = blockIdx.x * SCAN_B + threadIdx.x;
    int v = (i < N_NODES) ? cnt[i] : 0;
    sh[threadIdx.x] = v; __syncthreads();
    for (int off = 1; off < SCAN_B; off <<= 1) {
        int t = (threadIdx.x >= off) ? sh[threadIdx.x - off] : 0;
        __syncthreads();
        sh[threadIdx.x] += t;
        __syncthreads();
    }
    if (i < N_NODES) incl[i] = sh[threadIdx.x];
    if (threadIdx.x == SCAN_B - 1) bsum[blockIdx.x] = sh[threadIdx.x];
}
__global__ void scan2(int* __restrict__ bsum, int nb) {
    __shared__ int sh[128];
    int v = (threadIdx.x < nb) ? bsum[threadIdx.x] : 0;
    sh[threadIdx.x] = v; __syncthreads();
    for (int off = 1; off < 128; off <<= 1) {
        int t = (threadIdx.x >= off) ? sh[threadIdx.x - off] : 0;
        __syncthreads();
        sh[threadIdx.x] += t;
        __syncthreads();
    }
    if (threadIdx.x < nb) bsum[threadIdx.x] = sh[threadIdx.x] - v;  // exclusive
}
__global__ void scan3(const int* __restrict__ cnt, const int* __restrict__ incl,
                      const int* __restrict__ bsum, int* __restrict__ off,
                      int* __restrict__ cursor) {
    int i = blockIdx.x * blockDim.x + threadIdx.x;
    if (i < N_NODES) {
        int v = incl[i] - cnt[i] + bsum[i / SCAN_B];
        off[i] = v; cursor[i] = v;
    }
    if (i == 0) off[N_NODES] = N_EDGES;
}
__global__ void fill_kernel(const int* __restrict__ src, const int* __restrict__ dst,
                            int* __restrict__ cursor, int* __restrict__ esrc) {
    int e = blockIdx.x * blockDim.x + threadIdx.x;
    if (e < N_EDGES) {
        int pos = atomicAdd(&cursor[dst[e]], 1);
        esrc[pos] = src[e];
    }
}

// ---------------- gather: aggr[n] = sum over in-edges of h[src] ----------------
// wave per node; lane < 56 handles 4 cols (8B ushort4); cols >= 200 forced zero
__global__ __launch_bounds__(256) void gather_kernel(const __hip_bfloat16* __restrict__ h,
                                                     const int* __restrict__ off,
                                                     const int* __restrict__ esrc,
                                                     __hip_bfloat16* __restrict__ aggr) {
    int wave = threadIdx.x >> 6, lane = threadIdx.x & 63;
    int n = blockIdx.x * 4 + wave;
    if (n >= N_PAD) return;
    int col = lane * 4;
    bool store_l = (lane < 56);
    bool sum_l   = (col < D);     // lanes 0..49
    float a0 = 0, a1 = 0, a2 = 0, a3 = 0;
    if (n < N_NODES && sum_l) {
        int e0 = off[n], e1 = off[n + 1];
        int e = e0;
        for (; e + 1 < e1; e += 2) {
            const ushort4 v = *(const ushort4*)(h + (size_t)esrc[e] * KP + col);
            const ushort4 w = *(const ushort4*)(h + (size_t)esrc[e + 1] * KP + col);
            a0 += __bfloat162float(*(const __hip_bfloat16*)&v.x) + __bfloat162float(*(const __hip_bfloat16*)&w.x);
            a1 += __bfloat162float(*(const __hip_bfloat16*)&v.y) + __bfloat162float(*(const __hip_bfloat16*)&w.y);
            a2 += __bfloat162float(*(const __hip_bfloat16*)&v.z) + __bfloat162float(*(const __hip_bfloat16*)&w.z);
            a3 += __bfloat162float(*(const __hip_bfloat16*)&v.w) + __bfloat162float(*(const __hip_bfloat16*)&w.w);
        }
        if (e < e1) {
            const ushort4 v = *(const ushort4*)(h + (size_t)esrc[e] * KP + col);
            a0 += __bfloat162float(*(const __hip_bfloat16*)&v.x);
            a1 += __bfloat162float(*(const __hip_bfloat16*)&v.y);
            a2 += __bfloat162float(*(const __hip_bfloat16*)&v.z);
            a3 += __bfloat162float(*(const __hip_bfloat16*)&v.w);
        }
    }
    if (store_l) {
        __hip_bfloat16 o[4];
        o[0] = __float2bfloat16(a0); o[1] = __float2bfloat16(a1);
        o[2] = __float2bfloat16(a2); o[3] = __float2bfloat16(a3);
        *(ushort4*)(aggr + (size_t)n * KP + col) = *(const ushort4*)o;
    }
}

// ---------------- MFMA GRU: A/H in registers, B staged via LDS per j-tile ----------------
// grid N_PAD/128; block 256 = 4 waves; wave: 32 rows, sweeps 13 j-tiles x 6 gates
__global__ __launch_bounds__(256, 2) void gru_mfma(const __hip_bfloat16* __restrict__ aggr,
                                                   const __hip_bfloat16* __restrict__ hcur,
                                                   __hip_bfloat16* __restrict__ hnext,
                                                   int step) {
    __shared__ short Bs[2688 * 8];   // 43008 B: one jt tile, [g][t][lane][8]
    int tid = threadIdx.x;
    int lane = tid & 63, wave = tid >> 6;
    int mw = blockIdx.x * 128 + wave * 32;
    int mrow = lane & 15, kq = lane >> 4;
    size_t abase = (size_t)(mw + mrow) * KP + kq * 8;

    // load this wave's A/H fragments once (32 rows x 224 cols each)
    bfrag av[2][7], hv[2][7];
    #pragma unroll
    for (int mf = 0; mf < 2; ++mf)
        #pragma unroll
        for (int t = 0; t < 7; ++t) {
            av[mf][t] = *(const bfrag*)(aggr + abase + mf * 16 * KP + t * 32);
            hv[mf][t] = *(const bfrag*)(hcur + abase + mf * 16 * KP + t * 32);
        }

    const short* Wbase = g_Wall + (size_t)step * (6 * 13 * 7 * 64 * 8);
    int jcol = lane & 15;
    int rowq = (lane >> 4) * 4;

    for (int jt = 0; jt < 13; ++jt) {
        __syncthreads();   // previous jt's Bs reads complete
        // stage B tile for this jt: 2688 x 16B chunks, thread tid does chunks tid + i*256
        #pragma unroll
        for (int i = 0; i < 11; ++i) {
            int c = i * 256 + tid;
            if (c < 2688) {
                int g = c / 448;
                int r = c - g * 448;
                bfrag v = *(const bfrag*)(Wbase + (((size_t)(g * 13 + jt) * 448) + r) * 8);
                *(bfrag*)&Bs[(size_t)c * 8] = v;
            }
        }
        __syncthreads();   // Bs visible

        facc acc[6][2];
        #pragma unroll
        for (int g = 0; g < 6; ++g)
            #pragma unroll
            for (int mf = 0; mf < 2; ++mf) acc[g][mf] = (facc)(0.0f);

        #pragma unroll
        for (int t = 0; t < 7; ++t) {
            bfrag bv[6];
            #pragma unroll
            for (int g = 0; g < 6; ++g)
                bv[g] = *(const bfrag*)&Bs[(size_t)(((g * 7 + t) * 64) + lane) * 8];
            #pragma unroll
            for (int g = 0; g < 3; ++g)
                #pragma unroll
                for (int mf = 0; mf < 2; ++mf) {
                    acc[g][mf]     = __builtin_amdgcn_mfma_f32_16x16x32_bf16(av[mf][t], bv[g],     acc[g][mf],     0, 0, 0);
                    acc[g + 3][mf] = __builtin_amdgcn_mfma_f32_16x16x32_bf16(hv[mf][t], bv[g + 3], acc[g + 3][mf], 0, 0, 0);
                }
        }

        // epilogue: C/D layout col=lane&15 (j), row=(lane>>4)*4+reg (m)
        int j = jt * 16 + jcol;
        if (j < D) {
            float bir = g_bias[j],          biz = g_bias[DP + j],     bin = g_bias[2 * DP + j];
            float bhr = g_bias[3 * DP + j], bhz = g_bias[4 * DP + j], bhn = g_bias[5 * DP + j];
            #pragma unroll
            for (int mf = 0; mf < 2; ++mf) {
                int m0 = mw + mf * 16 + rowq;
                #pragma unroll
                for (int r = 0; r < 4; ++r) {
                    int m = m0 + r;
                    if (m < N_NODES) {
                        float hold = __bfloat162float(hcur[(size_t)m * KP + j]);
                        float rr = fast_sigmoid(acc[0][mf][r] + bir + acc[3][mf][r] + bhr);
                        float zz = fast_sigmoid(acc[1][mf][r] + biz + acc[4][mf][r] + bhz);
                        float nn = fast_tanh(acc[2][mf][r] + bin + rr * (acc[5][mf][r] + bhn));
                        hnext[(size_t)m * KP + j] = __float2bfloat16((1.0f - zz) * nn + zz * hold);
                    }
                }
            }
        }
    }
}

// ---------------- relu + column-max (bits trick, relu >= 0) ----------------
#define POOL_CHUNK 512
__global__ void pool_kernel(const __hip_bfloat16* __restrict__ h, unsigned int* __restrict__ pooled) {
    int d = threadIdx.x;
    if (d >= D) return;
    int n0 = blockIdx.x * POOL_CHUNK;
    float mx = 0.0f;
    for (int i = 0; i < POOL_CHUNK; ++i) {
        int n = n0 + i;
        if (n >= N_NODES) break;
        float v = __bfloat162float(h[(size_t)n * KP + d]);
        v = v > 0.0f ? v : 0.0f;
        mx = v > mx ? v : mx;
    }
    atomicMax(&pooled[d], __float_as_uint(mx));
}

// ---------------- logits + softmax ----------------
__global__ void head_kernel(const unsigned int* __restrict__ pooled,
                            const float* __restrict__ cls_w,
                            const float* __restrict__ cls_b,
                            float* __restrict__ out) {
    if (threadIdx.x == 0) {
        float l0 = cls_b[0], l1 = cls_b[1];
        for (int d = 0; d < D; ++d) {
            float p = __uint_as_float(pooled[d]);
            l0 += p * cls_w[d];
            l1 += p * cls_w[D + d];
        }
        float mx = l0 > l1 ? l0 : l1;
        float e0 = expf(l0 - mx), e1 = expf(l1 - mx);
        out[0] = e0 / (e0 + e1);
        out[1] = e1 / (e0 + e1);
    }
}

extern "C" void kernel_launch(void* const* d_in, const int* in_sizes, int n_in,
                              void* d_out, int out_size, void* d_ws, size_t ws_size,
                              hipStream_t stream) {
    const float* x     = (const float*)d_in[0];
    const float* W     = (const float*)d_in[1];
    const float* w_ih  = (const float*)d_in[2];
    const float* w_hh  = (const float*)d_in[3];
    const float* b_ih  = (const float*)d_in[4];
    const float* b_hh  = (const float*)d_in[5];
    const float* cls_w = (const float*)d_in[6];
    const float* cls_b = (const float*)d_in[7];
    const int*   ei    = (const int*)d_in[8];
    const int* src = ei;
    const int* dst = ei + N_EDGES;

    const size_t ROWB = (size_t)N_PAD * KP;     // bf16 elements per buffer
    __hip_bfloat16* hA   = (__hip_bfloat16*)d_ws;
    __hip_bfloat16* hB   = hA + ROWB;
    __hip_bfloat16* aggr = hB + ROWB;
    int* cnt    = (int*)(aggr + ROWB);
    int* incl   = cnt + N_NODES;
    int* bsum   = incl + N_NODES;
    int* off    = bsum + 128;
    int* cursor = off + N_NODES + 1;
    int* esrc   = cursor + N_NODES;
    unsigned int* pooled = (unsigned int*)(esrc + N_EDGES);

    // CSR build (once per call; edges are step-invariant)
    hipMemsetAsync(cnt, 0, N_NODES * sizeof(int), stream);
    count_kernel<<<(N_EDGES + 255) / 256, 256, 0, stream>>>(dst, cnt);
    scan1<<<(N_NODES + SCAN_B - 1) / SCAN_B, SCAN_B, 0, stream>>>(cnt, incl, bsum);
    scan2<<<1, 128, 0, stream>>>(bsum, (N_NODES + SCAN_B - 1) / SCAN_B);
    scan3<<<(N_NODES + 255) / 256, 256, 0, stream>>>(cnt, incl, bsum, off, cursor);
    fill_kernel<<<(N_EDGES + 255) / 256, 256, 0, stream>>>(src, dst, cursor, esrc);

    // weight prep
    wc_kernel<<<NUM_STEPS * 600, 256, 0, stream>>>(W, w_ih);
    wconv_kernel<<<(NUM_STEPS * 6 * 13 * 7 * 64) / 256, 256, 0, stream>>>(w_hh);
    bias_kernel<<<(6 * DP + 255) / 256, 256, 0, stream>>>(b_ih, b_hh);

    pad_kernel<<<(int)(ROWB / 256), 256, 0, stream>>>(x, hA);

    __hip_bfloat16* hcur = hA;
    __hip_bfloat16* hnext = hB;
    for (int s = 0; s < NUM_STEPS; ++s) {
        gather_kernel<<<N_PAD / 4, 256, 0, stream>>>(hcur, off, esrc, aggr);
        gru_mfma<<<N_PAD / 128, 256, 0, stream>>>(aggr, hcur, hnext, s);
        __hip_bfloat16* t = hcur; hcur = hnext; hnext = t;
    }
    hipMemsetAsync(pooled, 0, D * sizeof(unsigned int), stream);
    pool_kernel<<<(N_NODES + POOL_CHUNK - 1) / POOL_CHUNK, 256, 0, stream>>>(hcur, pooled);
    head_kernel<<<1, 64, 0, stream>>>(pooled, cls_w, cls_b, (float*)d_out);
}